// Round 4
// baseline (137.829 us; speedup 1.0000x reference)
//
#include <hip/hip_runtime.h>
#include <cmath>

// SSIM stability loss: 1 - mean(SSIM(x,y)), 11x11 Gaussian (sigma=1.5), zero SAME
// padding, fp32, 32 x 1 x 512 x 512.
//
// R18 config: 128 threads = 128 cols x 64-row band (4 blocks/CU = 4 independent
// 2-wave barrier domains), 74 H-rows streamed through a DOUBLE-BUFFERED 11-row
// LDS chunk of v4f (x0,y0,x1,y1) units (2 x 12.7 KB); 11-tap window read as 6
// ALIGNED ds_read_b128; lane parity folded into a 12-tap weight vector; packed
// v2f builtins; 11-deep circular register history for the vertical conv;
// ONE barrier per chunk (compute bufA || store bufB); single dispatch,
// fp64 atomic finish.
//
// R17 post-mortem: modulo-schedule neutral (compiler already hoists reads).
// Counter model now exact: VALU issue = 43% (measured 43.5), LDS pipe = 40%,
// neither saturated -> stall is barrier coupling at 2 blocks/CU. R18 attacks
// that: 4 smaller independent blocks + half the barriers at unchanged work.
// Predict: dur 50 -> 38-44us, VALUBusy ~52-60%, FETCH ~46MB, VGPR ~100-110.

#define IMG   512
#define BCOLS 128
#define BROWS 64
#define NHROW (BROWS + 10)   // 74 H-rows per band
#define NCHUNK 7             // ceil(74/11)
#define CHR   11             // rows per LDS chunk (== history depth)
#define LCOLS 144            // staged cols per row (covers c0-8 .. c0+135)
#define LUNITS 36            // float4 units per staged row per image
#define NUNITS (CHR * LUNITS)   // 396
#define NBLOCKS 1024
#define NPIX  8388608.0

typedef float v2f __attribute__((ext_vector_type(2)));
typedef float v4f __attribute__((ext_vector_type(4)));

struct GaussW { float w[11]; };

__global__ __launch_bounds__(128)
void ssim_stream_kernel(const float* __restrict__ x, const float* __restrict__ y,
                        double* __restrict__ acc_ws, unsigned long long* __restrict__ ctr,
                        float* __restrict__ out, GaussW gw) {
    // tile4[b][s][u] = LDS cols (2u, 2u+1) packed as (x0, y0, x1, y1); 16-B units
    __shared__ v4f tile4[2][CHR][LCOLS / 2];   // 2 * 11 * 72 * 16 = 25344 B
    __shared__ float wavesum[2];

    const int tid = threadIdx.x;
    const int c0 = blockIdx.x * BCOLS;
    const int r0 = blockIdx.y * BROWS;
    const size_t img_off = (size_t)blockIdx.z * (IMG * IMG);
    const float* __restrict__ xb = x + img_off;
    const float* __restrict__ yb = y + img_off;

    const int ci = tid;                 // output column; taps at LDS cols ci+3..ci+13
    const int ub = (ci + 3) >> 1;       // v4f unit of aligned window base
    const int p  = (ci + 3) & 1;        // parity: tap k sits at window pos p+k

    // 12-tap per-lane weight vector: window pos m covers LDS col 2*ub + m;
    // logical tap k = m - p, so wv2[m] = w[m-p] (0 outside [0,10]).
    v2f wv2[12];
    #pragma unroll
    for (int m = 0; m < 12; ++m) {
        float lo = (m <= 10) ? gw.w[m] : 0.f;       // p == 0
        float hi = (m >= 1) ? gw.w[m - 1] : 0.f;    // p == 1
        float wm = p ? hi : lo;
        wv2[m][0] = wm; wv2[m][1] = wm;
    }
    v2f wp[11];                          // vertical weights (parity-free)
    #pragma unroll
    for (int k = 0; k < 11; ++k) { wp[k][0] = gw.w[k]; wp[k][1] = gw.w[k]; }

    float4 sxr[4], syr[4];   // staged regs for next chunk (4 iters x 128 thr >= 396)

    auto load_chunk = [&](int c) {
        #pragma unroll
        for (int it = 0; it < 4; ++it) {
            int idx = tid + it * 128;
            int row = idx / LUNITS;
            int u   = idx - row * LUNITS;
            int gr = r0 - 5 + c * CHR + row;       // global image row
            int gc = c0 - 8 + u * 4;               // global col of float4 (16B aligned)
            float4 vx = make_float4(0.f, 0.f, 0.f, 0.f);
            float4 vy = vx;
            if (idx < NUNITS && (unsigned)gr < IMG && (unsigned)gc < IMG) {
                const float* px = xb + (size_t)gr * IMG + gc;
                const float* py = yb + (size_t)gr * IMG + gc;
                vx = *(const float4*)px;
                vy = *(const float4*)py;
            }
            sxr[it] = vx; syr[it] = vy;
        }
    };
    auto store_chunk = [&](int b) {
        #pragma unroll
        for (int it = 0; it < 4; ++it) {
            int idx = tid + it * 128;
            if (idx < NUNITS) {
                int row = idx / LUNITS;
                int u   = idx - row * LUNITS;
                tile4[b][row][u * 2]     = (v4f){sxr[it].x, syr[it].x, sxr[it].y, syr[it].y};
                tile4[b][row][u * 2 + 1] = (v4f){sxr[it].z, syr[it].z, sxr[it].w, syr[it].w};
            }
        }
    };

    v2f hist01[11];    // (hx, hy)
    v2f hist23[11];    // (hxx, hyy)
    float hist4[11];   // hxy
    float lsum = 0.f;
    const float C1 = 1e-4f, C2 = 9e-4f;

    load_chunk(0);
    store_chunk(0);
    __syncthreads();

    #pragma unroll 1
    for (int c = 0; c < NCHUNK; ++c) {      // 7 chunks x 11 rows = 77 >= 74
        const int b = c & 1;
        if (c < NCHUNK - 1) load_chunk(c + 1);  // global loads overlap chunk-c compute

        // compute one H-row from a prefetched 6-unit window register set
        auto compute_row = [&](int s, const v4f (&w6)[6]) {
            // --- horizontal conv: 12 taps ---
            v2f h01 = (v2f){0.f, 0.f};
            v2f h23 = (v2f){0.f, 0.f};
            float h4 = 0.f;
            #pragma unroll
            for (int m = 0; m < 12; ++m) {
                v2f t = (m & 1) ? w6[m >> 1].zw : w6[m >> 1].xy;
                v2f tw = wv2[m] * t;                          // v_pk_mul_f32
                h01 += tw;                                    // v_pk_add_f32
                h23 = __builtin_elementwise_fma(tw, t, h23);  // v_pk_fma_f32
                h4 = fmaf(tw[0], t[1], h4);                   // w*x*y (scalar)
            }
            hist01[s] = h01; hist23[s] = h23; hist4[s] = h4;

            // --- output row (11c + s - 10) completes now ---
            if (c > 0 || s == 10) {
                v2f a01 = (v2f){0.f, 0.f};
                v2f a23 = (v2f){0.f, 0.f};
                float a4 = 0.f;
                #pragma unroll
                for (int j = 0; j < 11; ++j) {
                    const int sl = (s + 1 + j) % 11;   // static per (s,j)
                    a01 = __builtin_elementwise_fma(wp[j], hist01[sl], a01);
                    a23 = __builtin_elementwise_fma(wp[j], hist23[sl], a23);
                    a4 = fmaf(wp[j][0], hist4[sl], a4);
                }
                float mx = a01[0], my = a01[1];
                float mxx = mx * mx, myy = my * my, mxy = mx * my;
                float sxx = a23[0] - mxx, syy = a23[1] - myy, sxy = a4 - mxy;
                float num = (2.f * mxy + C1) * (2.f * sxy + C2);
                float den = (mxx + myy + C1) * (sxx + syy + C2);
                lsum += num * __builtin_amdgcn_rcpf(den);
            }
        };

        // 2-row modulo schedule: disjoint wA/wB, reads issued one row ahead.
        v4f wA[6], wB[6];
        #pragma unroll
        for (int i = 0; i < 6; ++i) wA[i] = tile4[b][0][ub + i];

        const int base = c * CHR;
        #pragma unroll
        for (int s = 0; s < CHR; s += 2) {   // s = 0,2,4,6,8,10
            if (base + s < NHROW) {          // wave-uniform guard (last chunk: 8 rows)
                if (s + 1 < CHR) {
                    #pragma unroll
                    for (int i = 0; i < 6; ++i) wB[i] = tile4[b][s + 1][ub + i];
                }
                compute_row(s, wA);
            }
            if (s + 1 < CHR && base + s + 1 < NHROW) {
                if (s + 2 < CHR) {
                    #pragma unroll
                    for (int i = 0; i < 6; ++i) wA[i] = tile4[b][s + 2][ub + i];
                }
                compute_row(s + 1, wB);
            }
        }

        // write NEXT chunk into the other buffer while this one was being read;
        // one barrier makes the writes visible and releases this buffer.
        if (c < NCHUNK - 1) store_chunk(b ^ 1);
        __syncthreads();
    }

    // ---- reduction: wave shuffle -> LDS -> block partial -> fp64 atomic ----
    #pragma unroll
    for (int off = 32; off > 0; off >>= 1)
        lsum += __shfl_down(lsum, off, 64);
    if ((tid & 63) == 0) wavesum[tid >> 6] = lsum;
    __syncthreads();
    if (tid == 0) {
        float bs = wavesum[0] + wavesum[1];
        atomicAdd(acc_ws, (double)bs);
        __threadfence();
        unsigned long long old = atomicAdd(ctr, 1ull);
        if (old == (unsigned long long)(NBLOCKS - 1)) {
            __threadfence();
            double total = atomicAdd(acc_ws, 0.0);   // atomic RMW sees all prior adds
            out[0] = (float)(1.0 - total / NPIX);
        }
    }
}

extern "C" void kernel_launch(void* const* d_in, const int* in_sizes, int n_in,
                              void* d_out, int out_size, void* d_ws, size_t ws_size,
                              hipStream_t stream) {
    const float* x = (const float*)d_in[0];   // heatmap_clean
    const float* y = (const float*)d_in[1];   // heatmap_adv
    float* out = (float*)d_out;
    double* acc = (double*)d_ws;
    unsigned long long* ctr = (unsigned long long*)((char*)d_ws + 8);

    // zero the 16B of accumulator+counter state (capture-safe async memset)
    hipMemsetAsync(d_ws, 0, 16, stream);

    GaussW gw;
    double g[11], s = 0.0;
    for (int i = 0; i < 11; ++i) { double d = i - 5; g[i] = exp(-(d * d) / 4.5); s += g[i]; }
    for (int i = 0; i < 11; ++i) gw.w[i] = (float)(g[i] / s);

    dim3 grid(IMG / BCOLS, IMG / BROWS, 32);   // (4, 8, 32) = 1024 blocks = 4 per CU
    ssim_stream_kernel<<<grid, 128, 0, stream>>>(x, y, acc, ctr, out, gw);
}

// Round 5
// 120.788 us; speedup vs baseline: 1.1411x; 1.1411x over previous
//
#include <hip/hip_runtime.h>
#include <cmath>

// SSIM stability loss: 1 - mean(SSIM(x,y)), 11x11 Gaussian (sigma=1.5), zero SAME
// padding, fp32, 32 x 1 x 512 x 512.
//
// R19: sum/difference channel reformulation. SSIM only ever uses mx*my,
// mx^2+my^2, sigma_xy, sigma_x^2+sigma_y^2 -- so convolve u=(x+y)/sqrt2,
// v=(x-y)/sqrt2 and their squares (4 channels) instead of x,y,x^2,y^2,xy
// (5 channels):  Mu^2-Mv^2 = 2 mx my,  Mu^2+Mv^2 = mx^2+my^2,
//                Qu -Qv    = 2 E[xy],  Qu +Qv    = E[x^2]+E[y^2].
// H-conv: 3 packed ops/tap (was 4); V-conv: 2 pk_fma/slot (was 3) -> -35%
// VALU in the conv core. LDS layout/traffic unchanged ((u,v) in (x,y) slots).
//
// Structure = proven-best R11 shape: 256 threads = 256 cols x 64-row band,
// 74 H-rows streamed through an 11-row single-buffer LDS chunk of v4f
// (u0,v0,u1,v1) units; 6 ALIGNED ds_read_b128 per row; parity folded into a
// 12-tap weight vector; 11-deep circular register history; 512 blocks = 2/CU;
// single dispatch, fp64 atomic finish.
//
// Evidence: R15-R18 proved total VALU-busy time invariant (~23 us) across all
// occupancy/barrier/pipeline restructures, VALUBusy pinned ~44% -- duration
// tracks VALU work at fixed stall fraction. So shrink the work.
// Predict: dur 49-53 -> 36-40 us, VALUBusy ~40-46%, FETCH ~43.5MB, VGPR ~85.

#define IMG   512
#define BROWS 64
#define NHROW (BROWS + 10)   // 74 H-rows per band
#define NCHUNK 7             // ceil(74/11)
#define CHR   11             // rows per LDS chunk (== history depth)
#define LCOLS 272            // staged cols per row (covers c0-8 .. c0+263)
#define LUNITS 68            // float4 units per staged row
#define NUNITS (CHR * LUNITS)   // 748
#define NBLOCKS 512
#define NPIX  8388608.0
#define RSQRT2 0.70710678118654752f

typedef float v2f __attribute__((ext_vector_type(2)));
typedef float v4f __attribute__((ext_vector_type(4)));

struct GaussW { float w[11]; };

__global__ __launch_bounds__(256)
void ssim_stream_kernel(const float* __restrict__ x, const float* __restrict__ y,
                        double* __restrict__ acc_ws, unsigned long long* __restrict__ ctr,
                        float* __restrict__ out, GaussW gw) {
    // tile4[s][u] = LDS cols (2u, 2u+1) packed as (u0, v0, u1, v1); 16-B units
    __shared__ v4f tile4[CHR][LCOLS / 2];   // 11 * 136 * 16 = 23936 B
    __shared__ float wavesum[4];

    const int tid = threadIdx.x;
    const int c0 = blockIdx.x * 256;
    const int r0 = blockIdx.y * BROWS;
    const size_t img_off = (size_t)blockIdx.z * (IMG * IMG);
    const float* __restrict__ xb = x + img_off;
    const float* __restrict__ yb = y + img_off;

    const int ci = tid;                 // output column; taps at LDS cols ci+3..ci+13
    const int ub = (ci + 3) >> 1;       // v4f unit of aligned window base
    const int p  = (ci + 3) & 1;        // parity: tap k sits at window pos p+k

    // 12-tap per-lane weight vector: window pos m covers LDS col 2*ub + m;
    // logical tap k = m - p, so wv2[m] = w[m-p] (0 outside [0,10]).
    v2f wv2[12];
    #pragma unroll
    for (int m = 0; m < 12; ++m) {
        float lo = (m <= 10) ? gw.w[m] : 0.f;       // p == 0
        float hi = (m >= 1) ? gw.w[m - 1] : 0.f;    // p == 1
        float wm = p ? hi : lo;
        wv2[m][0] = wm; wv2[m][1] = wm;
    }
    v2f wp[11];                          // vertical weights (parity-free)
    #pragma unroll
    for (int k = 0; k < 11; ++k) { wp[k][0] = gw.w[k]; wp[k][1] = gw.w[k]; }

    float4 sxr[3], syr[3];   // staged regs for next chunk (3 iters x 256 thr >= 748)

    auto load_chunk = [&](int c) {
        #pragma unroll
        for (int it = 0; it < 3; ++it) {
            int idx = tid + it * 256;
            int row = idx / LUNITS;
            int u   = idx - row * LUNITS;
            int gr = r0 - 5 + c * CHR + row;       // global image row
            int gc = c0 - 8 + u * 4;               // global col of float4 (16B aligned)
            float4 vx = make_float4(0.f, 0.f, 0.f, 0.f);
            float4 vy = vx;
            if (idx < NUNITS && (unsigned)gr < IMG && (unsigned)gc < IMG) {
                const float* px = xb + (size_t)gr * IMG + gc;
                const float* py = yb + (size_t)gr * IMG + gc;
                vx = *(const float4*)px;
                vy = *(const float4*)py;
            }
            sxr[it] = vx; syr[it] = vy;
        }
    };
    // stage as u=(x+y)/sqrt2, v=(x-y)/sqrt2 (zero padding maps to zero: linear)
    auto store_chunk = [&]() {
        #pragma unroll
        for (int it = 0; it < 3; ++it) {
            int idx = tid + it * 256;
            if (idx < NUNITS) {
                int row = idx / LUNITS;
                int u   = idx - row * LUNITS;
                const float4 vx = sxr[it], vy = syr[it];
                tile4[row][u * 2]     = (v4f){(vx.x + vy.x) * RSQRT2, (vx.x - vy.x) * RSQRT2,
                                              (vx.y + vy.y) * RSQRT2, (vx.y - vy.y) * RSQRT2};
                tile4[row][u * 2 + 1] = (v4f){(vx.z + vy.z) * RSQRT2, (vx.z - vy.z) * RSQRT2,
                                              (vx.w + vy.w) * RSQRT2, (vx.w - vy.w) * RSQRT2};
            }
        }
    };

    v2f histL[11];     // (hu, hv)     -- linear channel H-conv results
    v2f histQ[11];     // (huu, hvv)   -- quadratic channel H-conv results
    float lsum = 0.f;
    const float C1 = 1e-4f, C2 = 9e-4f;

    load_chunk(0);
    store_chunk();
    __syncthreads();

    #pragma unroll 1
    for (int c = 0; c < NCHUNK; ++c) {      // 7 chunks x 11 rows = 77 >= 74
        if (c < NCHUNK - 1) load_chunk(c + 1);  // global loads overlap chunk-c compute

        #pragma unroll
        for (int s = 0; s < CHR; ++s) {     // H-row m = 11c + s; hist slot = s
            if (!(c == NCHUNK - 1 && s >= NHROW - (NCHUNK - 1) * CHR)) {   // m < 74
                v4f w6[6];
                #pragma unroll
                for (int i = 0; i < 6; ++i) w6[i] = tile4[s][ub + i];

                // --- horizontal conv: 12 taps, 3 packed ops each ---
                v2f hL = (v2f){0.f, 0.f};
                v2f hQ = (v2f){0.f, 0.f};
                #pragma unroll
                for (int m = 0; m < 12; ++m) {
                    v2f t = (m & 1) ? w6[m >> 1].zw : w6[m >> 1].xy;
                    hL = __builtin_elementwise_fma(wv2[m], t, hL);   // v_pk_fma_f32
                    v2f q = t * t;                                   // v_pk_mul_f32
                    hQ = __builtin_elementwise_fma(wv2[m], q, hQ);   // v_pk_fma_f32
                }
                histL[s] = hL; histQ[s] = hQ;

                // --- output row (11c + s - 10) completes now ---
                if (c > 0 || s == 10) {
                    v2f aL = (v2f){0.f, 0.f};
                    v2f aQ = (v2f){0.f, 0.f};
                    #pragma unroll
                    for (int j = 0; j < 11; ++j) {
                        const int sl = (s + 1 + j) % 11;   // static per (s,j)
                        aL = __builtin_elementwise_fma(wp[j], histL[sl], aL);
                        aQ = __builtin_elementwise_fma(wp[j], histQ[sl], aQ);
                    }
                    // Mu=aL[0], Mv=aL[1], Qu=aQ[0], Qv=aQ[1]
                    float a = aL[0] * aL[0], b = aL[1] * aL[1];
                    float dm = a - b;              // = 2 mx my
                    float sm = a + b;              // = mx^2 + my^2
                    float num = (dm + C1) * ((aQ[0] - aQ[1]) - dm + C2);  // 2sxy = dq-dm
                    float den = (sm + C1) * ((aQ[0] + aQ[1]) - sm + C2);  // sx2+sy2 = sq-sm
                    lsum += num * __builtin_amdgcn_rcpf(den);
                }
            }
        }

        __syncthreads();                    // everyone done reading tile
        if (c < NCHUNK - 1) { store_chunk(); __syncthreads(); }
    }

    // ---- reduction: wave shuffle -> LDS -> block partial -> fp64 atomic ----
    #pragma unroll
    for (int off = 32; off > 0; off >>= 1)
        lsum += __shfl_down(lsum, off, 64);
    if ((tid & 63) == 0) wavesum[tid >> 6] = lsum;
    __syncthreads();
    if (tid == 0) {
        float bs = wavesum[0] + wavesum[1] + wavesum[2] + wavesum[3];
        atomicAdd(acc_ws, (double)bs);
        __threadfence();
        unsigned long long old = atomicAdd(ctr, 1ull);
        if (old == (unsigned long long)(NBLOCKS - 1)) {
            __threadfence();
            double total = atomicAdd(acc_ws, 0.0);   // atomic RMW sees all prior adds
            out[0] = (float)(1.0 - total / NPIX);
        }
    }
}

extern "C" void kernel_launch(void* const* d_in, const int* in_sizes, int n_in,
                              void* d_out, int out_size, void* d_ws, size_t ws_size,
                              hipStream_t stream) {
    const float* x = (const float*)d_in[0];   // heatmap_clean
    const float* y = (const float*)d_in[1];   // heatmap_adv
    float* out = (float*)d_out;
    double* acc = (double*)d_ws;
    unsigned long long* ctr = (unsigned long long*)((char*)d_ws + 8);

    // zero the 16B of accumulator+counter state (capture-safe async memset)
    hipMemsetAsync(d_ws, 0, 16, stream);

    GaussW gw;
    double g[11], s = 0.0;
    for (int i = 0; i < 11; ++i) { double d = i - 5; g[i] = exp(-(d * d) / 4.5); s += g[i]; }
    for (int i = 0; i < 11; ++i) gw.w[i] = (float)(g[i] / s);

    dim3 grid(2, IMG / BROWS, 32);   // (2, 8, 32) = 512 blocks = 2 per CU
    ssim_stream_kernel<<<grid, 256, 0, stream>>>(x, y, acc, ctr, out, gw);
}

// Round 6
// 118.609 us; speedup vs baseline: 1.1620x; 1.0184x over previous
//
#include <hip/hip_runtime.h>
#include <cmath>

// SSIM stability loss: 1 - mean(SSIM(x,y)), 11x11 Gaussian (sigma=1.5), zero SAME
// padding, fp32, 32 x 1 x 512 x 512.
//
// R20: 2 output columns per thread, full-width blocks. Evidence: R19 showed
// VALU and the per-CU LDS pipe are CO-BINDING (~42% each; 931 MB LDS reads
// ~= 18 us pipe time ~= VALU busy time). Adjacent columns share 10/11 taps:
// one thread doing cols (2t,2t+1) reads 7 ds_read_b128/row for 2 cols
// (vs 12) -> -42% LDS traffic, and shares q=t*t across cols -> -22% H-VALU.
// Both columns have FIXED parity -> exact 11 taps, weight vector wp[11]
// shared between H and V conv (padded wv2[12] eliminated).
//
// Channels stay sum/difference (R19): u=(x+y)/sqrt2, v=(x-y)/sqrt2, squares.
// Structure: 256 threads x 512 cols (full width, no horizontal halo) x
// 64-row band; 74 H-rows streamed through DOUBLE-BUFFERED 11-row LDS chunks
// (2 x 46.4 KB, one barrier/chunk); 11-deep circular register history x 2
// cols; grid (8,32) = 256 blocks = 1/CU (8 waves/CU = 2/SIMD, unchanged).
// Predict: dur 42.6 -> 30-34 us, VALU ~42-50%, VGPR ~210 (watch WRITE_SIZE
// for spill regression), bank conflicts down.

#define IMG   512
#define BROWS 64
#define NHROW (BROWS + 10)   // 74 H-rows per band
#define NCHUNK 7             // ceil(74/11)
#define CHR   11             // rows per LDS chunk (== history depth)
#define LCOLS 528            // staged cols -8..519 (full width + halo)
#define LUNITS 132           // float4 units per staged row
#define NUNITS (CHR * LUNITS)   // 1452
#define NITER 6              // ceil(1452/256) staging iters
#define NBLOCKS 256
#define NPIX  8388608.0
#define RSQRT2 0.70710678118654752f

typedef float v2f __attribute__((ext_vector_type(2)));
typedef float v4f __attribute__((ext_vector_type(4)));

struct GaussW { float w[11]; };

__global__ __launch_bounds__(256)
void ssim_stream_kernel(const float* __restrict__ x, const float* __restrict__ y,
                        double* __restrict__ acc_ws, unsigned long long* __restrict__ ctr,
                        float* __restrict__ out, GaussW gw) {
    // tile4[b][s][u] = LDS cols (2u-8, 2u-7) packed as (u0, v0, u1, v1)
    __shared__ v4f tile4[2][CHR][LCOLS / 2];   // 2 * 11 * 264 * 16 = 92928 B
    __shared__ float wavesum[4];

    const int tid = threadIdx.x;
    const int r0 = blockIdx.x * BROWS;
    const size_t img_off = (size_t)blockIdx.y * (IMG * IMG);
    const float* __restrict__ xb = x + img_off;
    const float* __restrict__ yb = y + img_off;

    // thread handles output cols (2*tid, 2*tid+1). Their tap windows span LDS
    // cols 2*tid+3 .. 2*tid+14 = v4f units tid+1 .. tid+7 (fixed parity:
    // col A taps sit at window pos m=1..11, col B at m=2..12).
    const int ub = tid + 1;

    v2f wp[11];                          // weights, shared by H and V conv
    #pragma unroll
    for (int k = 0; k < 11; ++k) { wp[k][0] = gw.w[k]; wp[k][1] = gw.w[k]; }

    float4 sxr[NITER], syr[NITER];   // staged regs for next chunk

    auto load_chunk = [&](int c) {
        #pragma unroll
        for (int it = 0; it < NITER; ++it) {
            int idx = tid + it * 256;
            int row = idx / LUNITS;
            int u   = idx - row * LUNITS;
            int gr = r0 - 5 + c * CHR + row;       // global image row
            int gc = -8 + u * 4;                   // global col of float4 (16B aligned)
            float4 vx = make_float4(0.f, 0.f, 0.f, 0.f);
            float4 vy = vx;
            if (idx < NUNITS && (unsigned)gr < IMG && (unsigned)gc < IMG) {
                const float* px = xb + (size_t)gr * IMG + gc;
                const float* py = yb + (size_t)gr * IMG + gc;
                vx = *(const float4*)px;
                vy = *(const float4*)py;
            }
            sxr[it] = vx; syr[it] = vy;
        }
    };
    // stage as u=(x+y)/sqrt2, v=(x-y)/sqrt2 (zero padding maps to zero: linear)
    auto store_chunk = [&](int bb) {
        #pragma unroll
        for (int it = 0; it < NITER; ++it) {
            int idx = tid + it * 256;
            if (idx < NUNITS) {
                int row = idx / LUNITS;
                int u   = idx - row * LUNITS;
                const float4 vx = sxr[it], vy = syr[it];
                tile4[bb][row][u * 2]     = (v4f){(vx.x + vy.x) * RSQRT2, (vx.x - vy.x) * RSQRT2,
                                                  (vx.y + vy.y) * RSQRT2, (vx.y - vy.y) * RSQRT2};
                tile4[bb][row][u * 2 + 1] = (v4f){(vx.z + vy.z) * RSQRT2, (vx.z - vy.z) * RSQRT2,
                                                  (vx.w + vy.w) * RSQRT2, (vx.w - vy.w) * RSQRT2};
            }
        }
    };

    v2f histLA[11], histQA[11];   // col A: (hu,hv), (huu,hvv)
    v2f histLB[11], histQB[11];   // col B
    float lsum = 0.f;
    const float C1 = 1e-4f, C2 = 9e-4f;

    auto ssim_term = [&](v2f aL, v2f aQ) -> float {
        float a = aL[0] * aL[0], b = aL[1] * aL[1];
        float dm = a - b;              // = 2 mx my
        float sm = a + b;              // = mx^2 + my^2
        float num = (dm + C1) * ((aQ[0] - aQ[1]) - dm + C2);  // 2sxy
        float den = (sm + C1) * ((aQ[0] + aQ[1]) - sm + C2);  // sx2+sy2
        return num * __builtin_amdgcn_rcpf(den);
    };

    load_chunk(0);
    store_chunk(0);
    __syncthreads();

    #pragma unroll 1
    for (int c = 0; c < NCHUNK; ++c) {      // 7 chunks x 11 rows = 77 >= 74
        const int b = c & 1;
        if (c < NCHUNK - 1) load_chunk(c + 1);  // global loads overlap chunk-c compute

        #pragma unroll
        for (int s = 0; s < CHR; ++s) {     // H-row m = 11c + s; hist slot = s
            if (!(c == NCHUNK - 1 && s >= NHROW - (NCHUNK - 1) * CHR)) {   // m < 74
                v4f w7[7];
                #pragma unroll
                for (int i = 0; i < 7; ++i) w7[i] = tile4[b][s][ub + i];

                // --- horizontal conv, both cols, shared squares ---
                v2f hLA = (v2f){0.f, 0.f}, hQA = (v2f){0.f, 0.f};
                v2f hLB = (v2f){0.f, 0.f}, hQB = (v2f){0.f, 0.f};
                #pragma unroll
                for (int m = 1; m <= 12; ++m) {     // window pos (LDS col 2t+2+m)
                    v2f t = (m & 1) ? w7[m >> 1].zw : w7[m >> 1].xy;
                    v2f q = t * t;                                       // shared
                    if (m <= 11) {   // col A tap k = m-1
                        hLA = __builtin_elementwise_fma(wp[m - 1], t, hLA);
                        hQA = __builtin_elementwise_fma(wp[m - 1], q, hQA);
                    }
                    if (m >= 2) {    // col B tap k = m-2
                        hLB = __builtin_elementwise_fma(wp[m - 2], t, hLB);
                        hQB = __builtin_elementwise_fma(wp[m - 2], q, hQB);
                    }
                }
                histLA[s] = hLA; histQA[s] = hQA;
                histLB[s] = hLB; histQB[s] = hQB;

                // --- output row (11c + s - 10) completes now ---
                if (c > 0 || s == 10) {
                    v2f aLA = (v2f){0.f, 0.f}, aQA = (v2f){0.f, 0.f};
                    v2f aLB = (v2f){0.f, 0.f}, aQB = (v2f){0.f, 0.f};
                    #pragma unroll
                    for (int j = 0; j < 11; ++j) {
                        const int sl = (s + 1 + j) % 11;   // static per (s,j)
                        aLA = __builtin_elementwise_fma(wp[j], histLA[sl], aLA);
                        aQA = __builtin_elementwise_fma(wp[j], histQA[sl], aQA);
                        aLB = __builtin_elementwise_fma(wp[j], histLB[sl], aLB);
                        aQB = __builtin_elementwise_fma(wp[j], histQB[sl], aQB);
                    }
                    lsum += ssim_term(aLA, aQA);
                    lsum += ssim_term(aLB, aQB);
                }
            }
        }

        // write NEXT chunk into the other buffer, one barrier releases it
        if (c < NCHUNK - 1) store_chunk(b ^ 1);
        __syncthreads();
    }

    // ---- reduction: wave shuffle -> LDS -> block partial -> fp64 atomic ----
    #pragma unroll
    for (int off = 32; off > 0; off >>= 1)
        lsum += __shfl_down(lsum, off, 64);
    if ((tid & 63) == 0) wavesum[tid >> 6] = lsum;
    __syncthreads();
    if (tid == 0) {
        float bs = wavesum[0] + wavesum[1] + wavesum[2] + wavesum[3];
        atomicAdd(acc_ws, (double)bs);
        __threadfence();
        unsigned long long old = atomicAdd(ctr, 1ull);
        if (old == (unsigned long long)(NBLOCKS - 1)) {
            __threadfence();
            double total = atomicAdd(acc_ws, 0.0);   // atomic RMW sees all prior adds
            out[0] = (float)(1.0 - total / NPIX);
        }
    }
}

extern "C" void kernel_launch(void* const* d_in, const int* in_sizes, int n_in,
                              void* d_out, int out_size, void* d_ws, size_t ws_size,
                              hipStream_t stream) {
    const float* x = (const float*)d_in[0];   // heatmap_clean
    const float* y = (const float*)d_in[1];   // heatmap_adv
    float* out = (float*)d_out;
    double* acc = (double*)d_ws;
    unsigned long long* ctr = (unsigned long long*)((char*)d_ws + 8);

    // zero the 16B of accumulator+counter state (capture-safe async memset)
    hipMemsetAsync(d_ws, 0, 16, stream);

    GaussW gw;
    double g[11], s = 0.0;
    for (int i = 0; i < 11; ++i) { double d = i - 5; g[i] = exp(-(d * d) / 4.5); s += g[i]; }
    for (int i = 0; i < 11; ++i) gw.w[i] = (float)(g[i] / s);

    dim3 grid(IMG / BROWS, 32);   // (8, 32) = 256 blocks = 1 per CU
    ssim_stream_kernel<<<grid, 256, 0, stream>>>(x, y, acc, ctr, out, gw);
}

// Round 7
// 118.331 us; speedup vs baseline: 1.1648x; 1.0024x over previous
//
#include <hip/hip_runtime.h>
#include <cmath>

// SSIM stability loss: 1 - mean(SSIM(x,y)), 11x11 Gaussian (sigma=1.5), zero SAME
// padding, fp32, 32 x 1 x 512 x 512.
//
// R21: {2 cols/thread, 8 waves/CU} -- the untested cell of the TLP x ILP
// matrix. R20 proved the 2-col work savings are real (VALU-busy 17.9->16.0us,
// FETCH -11%) but its 93KB double-buffer capped residency at 1 blk/CU =
// 1 wave/SIMD (VALUBusy 34%). R21 keeps the 2-col inner loop and restores
// 2 blk/CU: SINGLE 46.5KB LDS buffer (2-barrier chunk structure, proven in
// R19) + BROWS=32 so grid = (16,32) = 512 blocks = 2/CU = 8 waves/CU.
// Cost: H-halo 42/32 = 1.3125 (+13.5% H work); still -7% VALU/px and -34%
// LDS-reads/px vs R19.
//
// Channels: sum/difference (R19): u=(x+y)/sqrt2, v=(x-y)/sqrt2 and squares;
// fixed parity -> exact 11 taps, single weight vector wp[11] for H and V.
// Predict: dur 47 -> 36-40us, VALUBusy ~44-48%, Occ ~14%, LDS ~46.6KB,
// FETCH ~44MB, VGPR ~132, WRITE_SIZE ~16B (no spill).

#define IMG   512
#define BROWS 32
#define NHROW (BROWS + 10)   // 42 H-rows per band
#define NCHUNK 4             // ceil(42/11)
#define CHR   11             // rows per LDS chunk (== history depth)
#define LCOLS 528            // staged cols -8..519 (full width + halo)
#define LUNITS 132           // float4 units per staged row
#define NUNITS (CHR * LUNITS)   // 1452
#define NITER 6              // ceil(1452/256) staging iters
#define NBLOCKS 512
#define NPIX  8388608.0
#define RSQRT2 0.70710678118654752f

typedef float v2f __attribute__((ext_vector_type(2)));
typedef float v4f __attribute__((ext_vector_type(4)));

struct GaussW { float w[11]; };

__global__ __launch_bounds__(256)
void ssim_stream_kernel(const float* __restrict__ x, const float* __restrict__ y,
                        double* __restrict__ acc_ws, unsigned long long* __restrict__ ctr,
                        float* __restrict__ out, GaussW gw) {
    // tile4[s][u] = LDS cols (2u-8, 2u-7) packed as (u0, v0, u1, v1)
    __shared__ v4f tile4[CHR][LCOLS / 2];   // 11 * 264 * 16 = 46464 B
    __shared__ float wavesum[4];

    const int tid = threadIdx.x;
    const int r0 = blockIdx.x * BROWS;
    const size_t img_off = (size_t)blockIdx.y * (IMG * IMG);
    const float* __restrict__ xb = x + img_off;
    const float* __restrict__ yb = y + img_off;

    // thread handles output cols (2*tid, 2*tid+1). Their tap windows span LDS
    // cols 2*tid+3 .. 2*tid+14 = v4f units tid+1 .. tid+7 (fixed parity:
    // col A taps at window pos m=1..11, col B at m=2..12).
    const int ub = tid + 1;

    v2f wp[11];                          // weights, shared by H and V conv
    #pragma unroll
    for (int k = 0; k < 11; ++k) { wp[k][0] = gw.w[k]; wp[k][1] = gw.w[k]; }

    float4 sxr[NITER], syr[NITER];   // staged regs for next chunk

    auto load_chunk = [&](int c) {
        #pragma unroll
        for (int it = 0; it < NITER; ++it) {
            int idx = tid + it * 256;
            int row = idx / LUNITS;
            int u   = idx - row * LUNITS;
            int gr = r0 - 5 + c * CHR + row;       // global image row
            int gc = -8 + u * 4;                   // global col of float4 (16B aligned)
            float4 vx = make_float4(0.f, 0.f, 0.f, 0.f);
            float4 vy = vx;
            if (idx < NUNITS && (unsigned)gr < IMG && (unsigned)gc < IMG) {
                const float* px = xb + (size_t)gr * IMG + gc;
                const float* py = yb + (size_t)gr * IMG + gc;
                vx = *(const float4*)px;
                vy = *(const float4*)py;
            }
            sxr[it] = vx; syr[it] = vy;
        }
    };
    // stage as u=(x+y)/sqrt2, v=(x-y)/sqrt2 (zero padding maps to zero: linear)
    auto store_chunk = [&]() {
        #pragma unroll
        for (int it = 0; it < NITER; ++it) {
            int idx = tid + it * 256;
            if (idx < NUNITS) {
                int row = idx / LUNITS;
                int u   = idx - row * LUNITS;
                const float4 vx = sxr[it], vy = syr[it];
                tile4[row][u * 2]     = (v4f){(vx.x + vy.x) * RSQRT2, (vx.x - vy.x) * RSQRT2,
                                              (vx.y + vy.y) * RSQRT2, (vx.y - vy.y) * RSQRT2};
                tile4[row][u * 2 + 1] = (v4f){(vx.z + vy.z) * RSQRT2, (vx.z - vy.z) * RSQRT2,
                                              (vx.w + vy.w) * RSQRT2, (vx.w - vy.w) * RSQRT2};
            }
        }
    };

    v2f histLA[11], histQA[11];   // col A: (hu,hv), (huu,hvv)
    v2f histLB[11], histQB[11];   // col B
    float lsum = 0.f;
    const float C1 = 1e-4f, C2 = 9e-4f;

    auto ssim_term = [&](v2f aL, v2f aQ) -> float {
        float a = aL[0] * aL[0], b = aL[1] * aL[1];
        float dm = a - b;              // = 2 mx my
        float sm = a + b;              // = mx^2 + my^2
        float num = (dm + C1) * ((aQ[0] - aQ[1]) - dm + C2);  // 2sxy
        float den = (sm + C1) * ((aQ[0] + aQ[1]) - sm + C2);  // sx2+sy2
        return num * __builtin_amdgcn_rcpf(den);
    };

    load_chunk(0);
    store_chunk();
    __syncthreads();

    #pragma unroll 1
    for (int c = 0; c < NCHUNK; ++c) {      // 4 chunks x 11 rows = 44 >= 42
        if (c < NCHUNK - 1) load_chunk(c + 1);  // global loads overlap chunk-c compute

        #pragma unroll
        for (int s = 0; s < CHR; ++s) {     // H-row m = 11c + s; hist slot = s
            if (!(c == NCHUNK - 1 && s >= NHROW - (NCHUNK - 1) * CHR)) {   // m < 42
                v4f w7[7];
                #pragma unroll
                for (int i = 0; i < 7; ++i) w7[i] = tile4[s][ub + i];

                // --- horizontal conv, both cols, shared squares ---
                v2f hLA = (v2f){0.f, 0.f}, hQA = (v2f){0.f, 0.f};
                v2f hLB = (v2f){0.f, 0.f}, hQB = (v2f){0.f, 0.f};
                #pragma unroll
                for (int m = 1; m <= 12; ++m) {     // window pos (LDS col 2t+2+m)
                    v2f t = (m & 1) ? w7[m >> 1].zw : w7[m >> 1].xy;
                    v2f q = t * t;                                       // shared
                    if (m <= 11) {   // col A tap k = m-1
                        hLA = __builtin_elementwise_fma(wp[m - 1], t, hLA);
                        hQA = __builtin_elementwise_fma(wp[m - 1], q, hQA);
                    }
                    if (m >= 2) {    // col B tap k = m-2
                        hLB = __builtin_elementwise_fma(wp[m - 2], t, hLB);
                        hQB = __builtin_elementwise_fma(wp[m - 2], q, hQB);
                    }
                }
                histLA[s] = hLA; histQA[s] = hQA;
                histLB[s] = hLB; histQB[s] = hQB;

                // --- output row (11c + s - 10) completes now ---
                if (c > 0 || s == 10) {
                    v2f aLA = (v2f){0.f, 0.f}, aQA = (v2f){0.f, 0.f};
                    v2f aLB = (v2f){0.f, 0.f}, aQB = (v2f){0.f, 0.f};
                    #pragma unroll
                    for (int j = 0; j < 11; ++j) {
                        const int sl = (s + 1 + j) % 11;   // static per (s,j)
                        aLA = __builtin_elementwise_fma(wp[j], histLA[sl], aLA);
                        aQA = __builtin_elementwise_fma(wp[j], histQA[sl], aQA);
                        aLB = __builtin_elementwise_fma(wp[j], histLB[sl], aLB);
                        aQB = __builtin_elementwise_fma(wp[j], histQB[sl], aQB);
                    }
                    lsum += ssim_term(aLA, aQA);
                    lsum += ssim_term(aLB, aQB);
                }
            }
        }

        __syncthreads();                    // everyone done reading tile
        if (c < NCHUNK - 1) { store_chunk(); __syncthreads(); }
    }

    // ---- reduction: wave shuffle -> LDS -> block partial -> fp64 atomic ----
    #pragma unroll
    for (int off = 32; off > 0; off >>= 1)
        lsum += __shfl_down(lsum, off, 64);
    if ((tid & 63) == 0) wavesum[tid >> 6] = lsum;
    __syncthreads();
    if (tid == 0) {
        float bs = wavesum[0] + wavesum[1] + wavesum[2] + wavesum[3];
        atomicAdd(acc_ws, (double)bs);
        __threadfence();
        unsigned long long old = atomicAdd(ctr, 1ull);
        if (old == (unsigned long long)(NBLOCKS - 1)) {
            __threadfence();
            double total = atomicAdd(acc_ws, 0.0);   // atomic RMW sees all prior adds
            out[0] = (float)(1.0 - total / NPIX);
        }
    }
}

extern "C" void kernel_launch(void* const* d_in, const int* in_sizes, int n_in,
                              void* d_out, int out_size, void* d_ws, size_t ws_size,
                              hipStream_t stream) {
    const float* x = (const float*)d_in[0];   // heatmap_clean
    const float* y = (const float*)d_in[1];   // heatmap_adv
    float* out = (float*)d_out;
    double* acc = (double*)d_ws;
    unsigned long long* ctr = (unsigned long long*)((char*)d_ws + 8);

    // zero the 16B of accumulator+counter state (capture-safe async memset)
    hipMemsetAsync(d_ws, 0, 16, stream);

    GaussW gw;
    double g[11], s = 0.0;
    for (int i = 0; i < 11; ++i) { double d = i - 5; g[i] = exp(-(d * d) / 4.5); s += g[i]; }
    for (int i = 0; i < 11; ++i) gw.w[i] = (float)(g[i] / s);

    dim3 grid(IMG / BROWS, 32);   // (16, 32) = 512 blocks = 2 per CU
    ssim_stream_kernel<<<grid, 256, 0, stream>>>(x, y, acc, ctr, out, gw);
}